// Round 8
// baseline (558.141 us; speedup 1.0000x reference)
//
#include <hip/hip_runtime.h>
#include <cstdint>

#define B_ 2
#define S_ 2048
#define D_ 768
#define H_ 12
#define DH_ 64
#define N_ 128

typedef unsigned short u16;
typedef unsigned int u32;
typedef unsigned long long u64;
typedef __attribute__((ext_vector_type(8))) short short8;
typedef __attribute__((ext_vector_type(4))) float f32x4;

#define MFMA16(a, b, c) __builtin_amdgcn_mfma_f32_16x16x32_bf16(a, b, c, 0, 0, 0)

__device__ inline u16 f2bf(float f) {
  union { float f; u32 u; } v; v.f = f;
  u32 r = v.u + 0x7FFFu + ((v.u >> 16) & 1u);
  return (u16)(r >> 16);
}
__device__ inline u32 pk2(float a, float b) {
  return (u32)f2bf(a) | ((u32)f2bf(b) << 16);
}
// HW packed f32->bf16 (RNE), lo=src0 hi=src1: 1 instr replaces ~9 VALU
__device__ inline u32 cvtpk(float lo, float hi) {
  u32 r;
  asm("v_cvt_pk_bf16_f32 %0, %1, %2" : "=v"(r) : "v"(lo), "v"(hi));
  return r;
}
__device__ inline float bf2f(u16 h) {
  union { u32 u; float f; } v; v.u = ((u32)h) << 16;
  return v.f;
}
__device__ inline float wredmax(float v) {
  #pragma unroll
  for (int o = 32; o > 0; o >>= 1) v = fmaxf(v, __shfl_down(v, o));
  return v;
}
__device__ inline float wredsum(float v) {
  #pragma unroll
  for (int o = 32; o > 0; o >>= 1) v += __shfl_down(v, o);
  return v;
}
__device__ inline void async_lds16(const u16* g, u16* l) {
  __builtin_amdgcn_global_load_lds((const __attribute__((address_space(1))) void*)g,
                                   (__attribute__((address_space(3))) void*)l, 16, 0, 0);
}

// ---------------- fp32 -> bf16 conversion, 8 elems/thread ----------------
__global__ void conv_bf16(const float* __restrict__ in, u16* __restrict__ outp, int n8) {
  int i = blockIdx.x * 256 + threadIdx.x;
  if (i >= n8) return;
  const float4* p = (const float4*)(in + (size_t)i * 8);
  float4 a = p[0], b = p[1];
  uint4 u;
  u.x = pk2(a.x, a.y); u.y = pk2(a.z, a.w); u.z = pk2(b.x, b.y); u.w = pk2(b.z, b.w);
  *(uint4*)(outp + (size_t)i * 8) = u;
}

// ================= pure-bf16 MFMA GEMM: C = A[M,K] @ W[N,K]^T + bias =================
template <int OUT_BF16>
__global__ __launch_bounds__(256) void gemm_bf16(
    const u16* __restrict__ A, int lda,
    const u16* __restrict__ W, int ldb,
    const float* __restrict__ bias,
    void* __restrict__ Cout, int ldc, int K) {
  __shared__ u16 As[128 * 32];
  __shared__ u16 Ws[128 * 32];
  const int tid = threadIdx.x;
  const int m0 = blockIdx.y * 128, n0 = blockIdx.x * 128;
  const int w = tid >> 6, lane = tid & 63;
  const int msub = (w & 1) * 64, nsub = (w >> 1) * 64;
  const int lrow = lane & 15, quad = lane >> 4;
  const int e0 = tid * 8;
  const int r0 = e0 >> 5, c0 = e0 & 31;
  const int e1 = e0 + 2048;
  const int r1 = e1 >> 5, c1 = e1 & 31;
  const u16* Ag0 = A + (size_t)(m0 + r0) * lda + c0;
  const u16* Ag1 = A + (size_t)(m0 + r1) * lda + c1;
  const u16* Wg0 = W + (size_t)(n0 + r0) * ldb + c0;
  const u16* Wg1 = W + (size_t)(n0 + r1) * ldb + c1;
  u16* AsB0 = As + (w << 9);
  u16* AsB1 = As + 2048 + (w << 9);
  u16* WsB0 = Ws + (w << 9);
  u16* WsB1 = Ws + 2048 + (w << 9);
  f32x4 zero = {0.f, 0.f, 0.f, 0.f};
  f32x4 acc[4][4];
  #pragma unroll
  for (int i = 0; i < 4; i++)
    #pragma unroll
    for (int j = 0; j < 4; j++) acc[i][j] = zero;
  for (int k0 = 0; k0 < K; k0 += 32) {
    __syncthreads();
    async_lds16(Ag0 + k0, AsB0);
    async_lds16(Ag1 + k0, AsB1);
    async_lds16(Wg0 + k0, WsB0);
    async_lds16(Wg1 + k0, WsB1);
    __syncthreads();
    short8 af[4], bf[4];
    #pragma unroll
    for (int i = 0; i < 4; i++)
      af[i] = *(const short8*)(As + (msub + i * 16 + lrow) * 32 + quad * 8);
    #pragma unroll
    for (int j = 0; j < 4; j++)
      bf[j] = *(const short8*)(Ws + (nsub + j * 16 + lrow) * 32 + quad * 8);
    #pragma unroll
    for (int i = 0; i < 4; i++)
      #pragma unroll
      for (int j = 0; j < 4; j++)
        acc[i][j] = MFMA16(af[i], bf[j], acc[i][j]);
  }
  #pragma unroll
  for (int i = 0; i < 4; i++) {
    #pragma unroll
    for (int j = 0; j < 4; j++) {
      int col = n0 + nsub + j * 16 + lrow;
      float bv = bias ? bias[col] : 0.f;
      #pragma unroll
      for (int r = 0; r < 4; r++) {
        int row = m0 + msub + i * 16 + quad * 4 + r;
        float val = acc[i][j][r] + bv;
        if (OUT_BF16) ((u16*)Cout)[(size_t)row * ldc + col] = f2bf(val);
        else ((float*)Cout)[(size_t)row * ldc + col] = val;
      }
    }
  }
}

// ================= V transpose: VT[b*12+h][d][s] = qkv[b][s][1536+h*64+d] =================
__global__ __launch_bounds__(256) void transpose_v(const u16* __restrict__ qkv, u16* __restrict__ VT) {
  __shared__ u16 t[64][72];
  const int z = blockIdx.y, b = z / 12, h = z - b * 12;
  const int s0 = blockIdx.x * 64;
  const int tid = threadIdx.x;
  {
    int r = tid >> 2, dp = (tid & 3) * 16;
    const u16* src = qkv + (size_t)b * 2048 * 2304 + (size_t)(s0 + r) * 2304 + 1536 + h * 64 + dp;
    *(uint4*)&t[r][dp] = *(const uint4*)src;
    *(uint4*)&t[r][dp + 8] = *(const uint4*)(src + 8);
  }
  __syncthreads();
  int d = tid >> 2, sp = (tid & 3) * 16;
  u16 vals[16];
  #pragma unroll
  for (int i = 0; i < 16; i++) vals[i] = t[sp + i][d];
  u16* dst = VT + ((size_t)z * 64 + d) * 2048 + s0 + sp;
  *(uint4*)dst = *(uint4*)&vals[0];
  *(uint4*)(dst + 8) = *(uint4*)&vals[8];
}

// ================= fused token attention (v10b: 256-VGPR cap + explicit prefetch) =====
// Same as v10 (r6, infra failure) with the prefetch clamped instead of conditional:
// no uninitialized registers; last iteration re-loads the final tile (L2-hot, free).
// Theory: at VGPR_Count=128 (compiler default for launch_bounds(512)) there are ~0
// regs for in-flight loads; LDS pins occupancy at 1 block/CU = 2 waves/SIMD, so a
// 256-VGPR cap via __launch_bounds__(512,2) is free and enables K[t+1]/VT[cc+1]
// prefetch to hide the ~200cy L2 latency.
__global__ __launch_bounds__(512, 2) void fused_tok_attn(
    const u16* __restrict__ qkv, const u16* __restrict__ VT,
    float* __restrict__ amF, u16* __restrict__ amH, u16* __restrict__ attnout) {
  __shared__ u16 pbuf[8 * 2 * 16 * 264];   // [wave][qsub][q=lrow][s-local 0..256)
  __shared__ float lred[8][2][16];
  __shared__ float obuf[2][2][16][66];     // [qsub][s-half][q][d]
  const int tid = threadIdx.x;
  const int w = tid >> 6, lane = tid & 63;
  const int lrow = lane & 15, quad = lane >> 4;
  // ---- XCD-aware decode: combo (b,z) -> XCD pair {2c, 2c+1} ----
  const int lid = blockIdx.x;
  const int xcd = lid & 7;
  const int combo = xcd >> 1;
  const int b = combo >> 1, z = combo & 1;
  const int q0 = (((lid >> 3) << 1) + (xcd & 1)) << 5;   // 32-row tile
  const int h0 = z * 6;
  const u16* qp = qkv + (size_t)b * 2048 * 2304;
  const u16* kp = qp + 768;
  const int strip = w * 256;               // pass-A ownership
  const int jj = w & 3, sh = w >> 2;       // pass-C ownership
  u16* ob = attnout + (size_t)b * 2048 * 768 + (size_t)q0 * 768;
  u16* pbA = pbuf + (w * 2 + 0) * 16 * 264;
  u16* pbB = pbuf + (w * 2 + 1) * 16 * 264;
  f32x4 zero = {0.f, 0.f, 0.f, 0.f};
  // head-mean accumulator: [qsub][c][e] -> am[q0+g*16+lrow][strip + c*32 + quad*8 + e]
  float amreg[2][8][8];
  #pragma unroll
  for (int g = 0; g < 2; g++)
    #pragma unroll
    for (int c = 0; c < 8; c++)
      #pragma unroll
      for (int e = 0; e < 8; e++) amreg[g][c][e] = 0.f;
  for (int hh = 0; hh < 6; hh++) {
    const int h = h0 + hh;
    const u16* qhA = qp + (size_t)(q0 + lrow) * 2304 + h * 64 + quad * 8;
    const u16* qhB = qp + (size_t)(q0 + 16 + lrow) * 2304 + h * 64 + quad * 8;
    short8 qfA0 = *(const short8*)qhA;
    short8 qfA1 = *(const short8*)(qhA + 32);
    short8 qfB0 = *(const short8*)qhB;
    short8 qfB1 = *(const short8*)(qhB + 32);
    // ---- pass A: S^T = mfma(K,Q), shared K loads, K[t+1] prefetched (clamped) ----
    float lsumA = 0.f, lsumB = 0.f;
    const u16* khbase = kp + (size_t)(strip + lrow) * 2304 + h * 64 + quad * 8;
    short8 kf0 = *(const short8*)khbase;
    short8 kf1 = *(const short8*)(khbase + 32);
    #pragma unroll
    for (int t = 0; t < 16; t++) {
      const int tn = (t < 15) ? (t + 1) : 15;
      const u16* khn = khbase + (size_t)tn * 16 * 2304;
      short8 kn0 = *(const short8*)khn;
      short8 kn1 = *(const short8*)(khn + 32);
      f32x4 svA = zero, svB = zero;
      svA = MFMA16(kf0, qfA0, svA);   // D[s][q]: lane -> q=lrow, s=t*16+quad*4+r
      svA = MFMA16(kf1, qfA1, svA);
      svB = MFMA16(kf0, qfB0, svB);
      svB = MFMA16(kf1, qfB1, svB);
      float a0 = __expf(svA[0] * 0.125f);
      float a1 = __expf(svA[1] * 0.125f);
      float a2 = __expf(svA[2] * 0.125f);
      float a3 = __expf(svA[3] * 0.125f);
      float b0 = __expf(svB[0] * 0.125f);
      float b1 = __expf(svB[1] * 0.125f);
      float b2 = __expf(svB[2] * 0.125f);
      float b3 = __expf(svB[3] * 0.125f);
      lsumA += (a0 + a1) + (a2 + a3);
      lsumB += (b0 + b1) + (b2 + b3);
      u32 wA0 = cvtpk(a0, a1), wA1 = cvtpk(a2, a3);
      u32 wB0 = cvtpk(b0, b1), wB1 = cvtpk(b2, b3);
      *(u64*)(pbA + lrow * 264 + t * 16 + quad * 4) = (u64)wA0 | ((u64)wA1 << 32);
      *(u64*)(pbB + lrow * 264 + t * 16 + quad * 4) = (u64)wB0 | ((u64)wB1 << 32);
      kf0 = kn0; kf1 = kn1;
    }
    lsumA += __shfl_xor(lsumA, 16);
    lsumA += __shfl_xor(lsumA, 32);
    lsumB += __shfl_xor(lsumB, 16);
    lsumB += __shfl_xor(lsumB, 32);
    if (lane < 16) { lred[w][0][lane] = lsumA; lred[w][1][lane] = lsumB; }
    __syncthreads();  // barrier1: pbuf + lred visible to all waves
    float invqA, invqB;
    float inv4A[4], inv4B[4];
    {
      float sA = 0.f, sB = 0.f;
      #pragma unroll
      for (int w2 = 0; w2 < 8; w2++) { sA += lred[w2][0][lrow]; sB += lred[w2][1][lrow]; }
      invqA = 1.f / sA; invqB = 1.f / sB;
      #pragma unroll
      for (int r = 0; r < 4; r++) {
        float rA = 0.f, rB = 0.f;
        #pragma unroll
        for (int w2 = 0; w2 < 8; w2++) {
          rA += lred[w2][0][quad * 4 + r];
          rB += lred[w2][1][quad * 4 + r];
        }
        inv4A[r] = 1.f / rA; inv4B[r] = 1.f / rB;
      }
    }
    // ---- am accumulate from own strip's bf16 P (both q-subs) ----
    #pragma unroll
    for (int c = 0; c < 8; c++) {
      short8 pfa = *(const short8*)(pbA + lrow * 264 + c * 32 + quad * 8);
      short8 pfb = *(const short8*)(pbB + lrow * 264 + c * 32 + quad * 8);
      #pragma unroll
      for (int e = 0; e < 8; e++) {
        amreg[0][c][e] += bf2f((u16)pfa[e]) * invqA;
        amreg[1][c][e] += bf2f((u16)pfb[e]) * invqB;
      }
    }
    // ---- pass C: wave owns (d-quarter jj, s-half sh); VT[cc+1] prefetched (clamped) --
    f32x4 oA = zero, oB = zero;
    {
      const u16* vtp = VT + (size_t)(b * 12 + h) * 64 * 2048;
      const u16* vbase = vtp + (size_t)(jj * 16 + lrow) * 2048 + sh * 1024 + quad * 8;
      short8 vf = *(const short8*)vbase;
      #pragma unroll
      for (int cc = 0; cc < 32; cc++) {
        const int cn = (cc < 31) ? (cc + 1) : 31;
        short8 vn = *(const short8*)(vbase + cn * 32);
        const u16* pba = pbuf + (((4 * sh + (cc >> 3)) * 2 + 0) * 16 * 264) + lrow * 264 + (cc & 7) * 32 + quad * 8;
        const u16* pbb = pba + 16 * 264;
        oA = MFMA16(*(const short8*)pba, vf, oA);
        oB = MFMA16(*(const short8*)pbb, vf, oB);
        vf = vn;
      }
    }
    #pragma unroll
    for (int r = 0; r < 4; r++) {
      obuf[0][sh][quad * 4 + r][jj * 16 + lrow] = oA[r] * inv4A[r];
      obuf[1][sh][quad * 4 + r][jj * 16 + lrow] = oB[r] * inv4B[r];
    }
    __syncthreads();  // barrier2: obuf complete; pbuf reads done -> safe to rewrite
    #pragma unroll
    for (int ee = 0; ee < 4; ee++) {
      int e2 = tid + ee * 512;
      int row = e2 >> 6, col = e2 & 63;
      int g = row >> 4, rr = row & 15;
      float s = obuf[g][0][rr][col] + obuf[g][1][rr][col];
      ob[(size_t)row * 768 + h * 64 + col] = f2bf(s);
    }
    // next head's pbuf writes ordered after this head's reads via barrier2;
    // next head's obuf writes ordered after these reads via its barrier1.
  }
  // ---- am partial write (raw sums over this half's 6 heads) ----
  if (z == 0) {
    #pragma unroll
    for (int g = 0; g < 2; g++) {
      float* ar = amF + ((size_t)b * 2048 + q0 + g * 16 + lrow) * 2048 + strip;
      #pragma unroll
      for (int c = 0; c < 8; c++) {
        float4 v0 = {amreg[g][c][0], amreg[g][c][1], amreg[g][c][2], amreg[g][c][3]};
        float4 v1 = {amreg[g][c][4], amreg[g][c][5], amreg[g][c][6], amreg[g][c][7]};
        *(float4*)(ar + c * 32 + quad * 8) = v0;
        *(float4*)(ar + c * 32 + quad * 8 + 4) = v1;
      }
    }
  } else {
    #pragma unroll
    for (int g = 0; g < 2; g++) {
      u16* ar = amH + ((size_t)b * 2048 + q0 + g * 16 + lrow) * 2048 + strip;
      #pragma unroll
      for (int c = 0; c < 8; c++) {
        uint4 u;
        u.x = pk2(amreg[g][c][0], amreg[g][c][1]);
        u.y = pk2(amreg[g][c][2], amreg[g][c][3]);
        u.z = pk2(amreg[g][c][4], amreg[g][c][5]);
        u.w = pk2(amreg[g][c][6], amreg[g][c][7]);
        *(uint4*)(ar + c * 32 + quad * 8) = u;
      }
    }
  }
}

// ================= combine am halves: amF = (amF + bf16(amH)) / 12, in place ==========
__global__ void combine_am(float* __restrict__ amF, const u16* __restrict__ amH) {
  size_t i = ((size_t)blockIdx.x * 256 + threadIdx.x) * 8;
  float4 a0 = *(float4*)(amF + i);
  float4 a1 = *(float4*)(amF + i + 4);
  uint4 hb = *(const uint4*)(amH + i);
  const float c12 = 1.f / 12.f;
  float4 r0, r1;
  r0.x = (a0.x + bf2f((u16)(hb.x & 0xffff))) * c12;
  r0.y = (a0.y + bf2f((u16)(hb.x >> 16))) * c12;
  r0.z = (a0.z + bf2f((u16)(hb.y & 0xffff))) * c12;
  r0.w = (a0.w + bf2f((u16)(hb.y >> 16))) * c12;
  r1.x = (a1.x + bf2f((u16)(hb.z & 0xffff))) * c12;
  r1.y = (a1.y + bf2f((u16)(hb.z >> 16))) * c12;
  r1.z = (a1.z + bf2f((u16)(hb.w & 0xffff))) * c12;
  r1.w = (a1.w + bf2f((u16)(hb.w >> 16))) * c12;
  *(float4*)(amF + i) = r0;
  *(float4*)(amF + i + 4) = r1;
}

// ================= QK^T MFMA (node + cross) =================
__global__ __launch_bounds__(256) void qk_mfma(
    const u16* __restrict__ Q, int ldq, long qbs,
    const u16* __restrict__ Kp, int ldk, long kbs,
    float* __restrict__ S, long szs, int Sk, int nh, float scale) {
  __shared__ u16 Qs[128 * 72];
  __shared__ u16 Ks[128 * 72];
  const int tid = threadIdx.x;
  const int z = blockIdx.z, bb = z / nh, h = z - bb * nh;
  const u16* qp = Q + (size_t)bb * qbs + h * 64;
  const u16* kp = Kp + (size_t)bb * kbs + h * 64;
  float* sp = S + (size_t)z * szs;
  const int m0 = blockIdx.y * 128, n0 = blockIdx.x * 128;
  const int w = tid >> 6, lane = tid & 63;
  const int msub = (w & 1) * 64, nsub = (w >> 1) * 64;
  const int lrow = lane & 15, quad = lane >> 4;
  const int srow = tid >> 1, shalf = tid & 1;
  {
    const uint4* qg = (const uint4*)(qp + (size_t)(m0 + srow) * ldq + shalf * 32);
    const uint4* kg = (const uint4*)(kp + (size_t)(n0 + srow) * ldk + shalf * 32);
    uint4* qd = (uint4*)(Qs + srow * 72 + shalf * 32);
    uint4* kd = (uint4*)(Ks + srow * 72 + shalf * 32);
    #pragma unroll
    for (int u = 0; u < 4; u++) { qd[u] = qg[u]; kd[u] = kg[u]; }
  }
  __syncthreads();
  f32x4 zero = {0.f, 0.f, 0.f, 0.f};
  f32x4 acc[4][4];
  #pragma unroll
  for (int i = 0; i < 4; i++)
    #pragma unroll
    for (int j = 0; j < 4; j++) acc[i][j] = zero;
  #pragma unroll
  for (int ks = 0; ks < 2; ks++) {
    short8 af[4], bf[4];
    #pragma unroll
    for (int i = 0; i < 4; i++)
      af[i] = *(const short8*)(Qs + (msub + i * 16 + lrow) * 72 + ks * 32 + quad * 8);
    #pragma unroll
    for (int j = 0; j < 4; j++)
      bf[j] = *(const short8*)(Ks + (nsub + j * 16 + lrow) * 72 + ks * 32 + quad * 8);
    #pragma unroll
    for (int i = 0; i < 4; i++)
      #pragma unroll
      for (int j = 0; j < 4; j++)
        acc[i][j] = MFMA16(af[i], bf[j], acc[i][j]);
  }
  #pragma unroll
  for (int i = 0; i < 4; i++)
    #pragma unroll
    for (int j = 0; j < 4; j++) {
      int col = n0 + nsub + j * 16 + lrow;
      #pragma unroll
      for (int r = 0; r < 4; r++) {
        int row = m0 + msub + i * 16 + quad * 4 + r;
        sp[(size_t)row * Sk + col] = acc[i][j][r] * scale;
      }
    }
}

// ================= small softmax (Sk=128): node + cross; P->bf16 in place ==============
__global__ __launch_bounds__(128) void softmax_small(
    float* __restrict__ Sc, float* __restrict__ wout, int Sq) {
  const int q = blockIdx.x, b = blockIdx.y, tid = threadIdx.x;
  const int w = tid >> 6, lane = tid & 63;
  __shared__ float red[2];
  float am = 0.f;
  const size_t plane = (size_t)Sq * 128;
  for (int h = 0; h < 12; h++) {
    const int z = b * 12 + h;
    float* row = Sc + (size_t)z * plane + (size_t)q * 128;
    float v = row[tid];
    float m = wredmax(v);
    if (lane == 0) red[w] = m;
    __syncthreads();
    m = fmaxf(red[0], red[1]);
    float e = __expf(v - m);
    float s = wredsum(e);
    __syncthreads();
    if (lane == 0) red[w] = s;
    __syncthreads();
    float p = e / (red[0] + red[1]);
    ((u16*)(Sc + (size_t)z * plane))[(size_t)q * 256 + tid] = f2bf(p);
    am += p;
    __syncthreads();
  }
  wout[((size_t)b * Sq + q) * 128 + tid] = am * (1.f / 12.f);
}

// ================= small PV (Sk=128): Out[b, m, h*64+d] bf16, direct =================
__global__ __launch_bounds__(256) void pv_small(
    const u16* __restrict__ Pb, long pzs,
    const u16* __restrict__ KVb, int ldv, long vbs, int vhoff,
    u16* __restrict__ Outb, long obs) {
  __shared__ u16 Ps[128 * 40];
  __shared__ u16 Vs[64 * 40];
  const int tid = threadIdx.x;
  const int z = blockIdx.y, b = z / 12, h = z - b * 12;
  const u16* Pp = Pb + (size_t)z * pzs;
  const u16* Vp = KVb + (size_t)b * vbs + vhoff + h * 64;
  u16* Op = Outb + (size_t)b * obs + h * 64;
  const int m0 = blockIdx.x * 128;
  const int w = tid >> 6, lane = tid & 63;
  const int msub = w * 32;
  const int lrow = lane & 15, quad = lane >> 4;
  const int srow = tid >> 1, shalf = tid & 1;
  const int vk = tid >> 3, vn = (tid & 7) * 8;
  f32x4 zero = {0.f, 0.f, 0.f, 0.f};
  f32x4 acc[2][4];
  #pragma unroll
  for (int i = 0; i < 2; i++)
    #pragma unroll
    for (int j = 0; j < 4; j++) acc[i][j] = zero;
  #pragma unroll
  for (int k0 = 0; k0 < 128; k0 += 32) {
    uint4 pa = *(const uint4*)(Pp + (size_t)(m0 + srow) * 256 + k0 + shalf * 16);
    uint4 pb2 = *(const uint4*)(Pp + (size_t)(m0 + srow) * 256 + k0 + shalf * 16 + 8);
    uint4 vv = *(const uint4*)(Vp + (size_t)(k0 + vk) * ldv + vn);
    __syncthreads();
    *(uint4*)(Ps + srow * 40 + shalf * 16) = pa;
    *(uint4*)(Ps + srow * 40 + shalf * 16 + 8) = pb2;
    const u16* vs = (const u16*)&vv;
    #pragma unroll
    for (int u = 0; u < 8; u++) Vs[(vn + u) * 40 + vk] = vs[u];
    __syncthreads();
    short8 af[2], bf[4];
    #pragma unroll
    for (int i = 0; i < 2; i++)
      af[i] = *(const short8*)(Ps + (msub + i * 16 + lrow) * 40 + quad * 8);
    #pragma unroll
    for (int j = 0; j < 4; j++)
      bf[j] = *(const short8*)(Vs + (j * 16 + lrow) * 40 + quad * 8);
    #pragma unroll
    for (int i = 0; i < 2; i++)
      #pragma unroll
      for (int j = 0; j < 4; j++)
        acc[i][j] = MFMA16(af[i], bf[j], acc[i][j]);
  }
  #pragma unroll
  for (int i = 0; i < 2; i++)
    #pragma unroll
    for (int j = 0; j < 4; j++) {
      int col = j * 16 + lrow;
      #pragma unroll
      for (int r = 0; r < 4; r++) {
        int row = m0 + msub + i * 16 + quad * 4 + r;
        Op[(size_t)row * D_ + col] = f2bf(acc[i][j][r]);
      }
    }
}

// ================= LayerNorm of (x1 + x2) with optional bf16 twin =================
__global__ void ln_kernel(const float* __restrict__ x1, const float* __restrict__ x2,
                          const float* __restrict__ g, const float* __restrict__ bt,
                          float* __restrict__ outp, u16* __restrict__ outbf) {
  const int row = blockIdx.x;
  const int tid = threadIdx.x;
  __shared__ float red[8];
  float v[3];
  #pragma unroll
  for (int j = 0; j < 3; j++) {
    int c = tid + j * 256;
    v[j] = x1[(size_t)row * D_ + c] + x2[(size_t)row * D_ + c];
  }
  float s = v[0] + v[1] + v[2];
  s = wredsum(s);
  int wid = tid >> 6, lane = tid & 63;
  if (lane == 0) red[wid] = s;
  __syncthreads();
  float mean = (red[0] + red[1] + red[2] + red[3]) / 768.f;
  float d0 = v[0] - mean, d1 = v[1] - mean, d2 = v[2] - mean;
  float q = d0 * d0 + d1 * d1 + d2 * d2;
  q = wredsum(q);
  if (lane == 0) red[4 + wid] = q;
  __syncthreads();
  float var = (red[4] + red[5] + red[6] + red[7]) / 768.f;
  float inv = rsqrtf(var + 1e-5f);
  #pragma unroll
  for (int j = 0; j < 3; j++) {
    int c = tid + j * 256;
    float val = (v[j] - mean) * inv * g[c] + bt[c];
    outp[(size_t)row * D_ + c] = val;
    if (outbf) outbf[(size_t)row * D_ + c] = f2bf(val);
  }
}

// ================= w = mean over q of tok_attn (two-stage) =================
__global__ void colmean_part(const float* __restrict__ ta, float* __restrict__ part) {
  int b = blockIdx.y, z = blockIdx.z;
  int k = blockIdx.x * 256 + threadIdx.x;
  const float* p = ta + (size_t)b * S_ * S_ + (size_t)z * 256 * S_ + k;
  float s = 0.f;
  #pragma unroll 8
  for (int q = 0; q < 256; q++) s += p[(size_t)q * S_];
  part[((size_t)z * B_ + b) * S_ + k] = s;
}

__global__ void colmean_final(const float* __restrict__ part, float* __restrict__ w) {
  int b = blockIdx.y;
  int k = blockIdx.x * 256 + threadIdx.x;
  float s = 0.f;
  #pragma unroll
  for (int z = 0; z < 8; z++) s += part[((size_t)z * B_ + b) * S_ + k];
  w[b * S_ + k] = s * (1.f / (float)S_);
}

// ================= segment aggregation (seg sorted per batch) =================
__global__ void aggregate_kernel(const float* __restrict__ x, const float* __restrict__ w,
                                 const int* __restrict__ seg, float* __restrict__ outp,
                                 u16* __restrict__ outbf) {
  const int b = blockIdx.y, n = blockIdx.x;
  const int* sg = seg + b * S_;
  int l = 0, rr = S_;
  while (l < rr) { int mid = (l + rr) >> 1; if (sg[mid] < n) l = mid + 1; else rr = mid; }
  const int lo = l;
  rr = S_;
  while (l < rr) { int mid = (l + rr) >> 1; if (sg[mid] < n + 1) l = mid + 1; else rr = mid; }
  const int hi = l;
  const int tid = threadIdx.x;
  float acc[3] = {0.f, 0.f, 0.f};
  float den = 0.f;
  for (int s = lo; s < hi; s++) {
    float ww = w[b * S_ + s];
    den += ww;
    const float* xr = x + (size_t)(b * S_ + s) * D_;
    #pragma unroll
    for (int j = 0; j < 3; j++) acc[j] += ww * xr[tid + j * 256];
  }
  float invd = 1.f / (den + 1e-8f);
  size_t ro = (size_t)(b * N_ + n) * D_;
  #pragma unroll
  for (int j = 0; j < 3; j++) {
    float val = acc[j] * invd;
    outp[ro + tid + j * 256] = val;
    outbf[ro + tid + j * 256] = f2bf(val);
  }
}

// ================= enhanced = tokout + cross_proj + gather(node_emb), bf16 out ==========
__global__ void enhanced_kernel(const float* __restrict__ tokout, const float* __restrict__ crossp,
                                const float* __restrict__ nodeemb, const int* __restrict__ seg,
                                u16* __restrict__ outbf) {
  int g8 = blockIdx.x * 256 + threadIdx.x;
  int bs = g8 / 96, d0 = (g8 - bs * 96) * 8;
  int b = bs >> 11;
  int n = seg[bs];
  const float* t = tokout + (size_t)bs * D_ + d0;
  const float* cp = crossp + (size_t)bs * D_ + d0;
  const float* ne = nodeemb + (size_t)(b * N_ + n) * D_ + d0;
  float4 a0 = *(const float4*)t, a1 = *(const float4*)(t + 4);
  float4 b0 = *(const float4*)cp, b1 = *(const float4*)(cp + 4);
  float4 c0 = *(const float4*)ne, c1 = *(const float4*)(ne + 4);
  uint4 u;
  u.x = pk2(a0.x + b0.x + c0.x, a0.y + b0.y + c0.y);
  u.y = pk2(a0.z + b0.z + c0.z, a0.w + b0.w + c0.w);
  u.z = pk2(a1.x + b1.x + c1.x, a1.y + b1.y + c1.y);
  u.w = pk2(a1.z + b1.z + c1.z, a1.w + b1.w + c1.w);
  *(uint4*)(outbf + (size_t)g8 * 8) = u;
}

extern "C" void kernel_launch(void* const* d_in, const int* in_sizes, int n_in,
                              void* d_out, int out_size, void* d_ws, size_t ws_size,
                              hipStream_t stream) {
  const float* hs     = (const float*)d_in[0];
  const int*   t2s    = (const int*)d_in[1];
  const float* Wqkv_t = (const float*)d_in[2];
  const float* bqkv_t = (const float*)d_in[3];
  const float* Wo_t   = (const float*)d_in[4];
  const float* bo_t   = (const float*)d_in[5];
  const float* Wqkv_c = (const float*)d_in[6];
  const float* bqkv_c = (const float*)d_in[7];
  const float* Wo_c   = (const float*)d_in[8];
  const float* bo_c   = (const float*)d_in[9];
  const float* g_tok  = (const float*)d_in[10];
  const float* b_tok  = (const float*)d_in[11];
  const float* g_node = (const float*)d_in[12];
  const float* b_node = (const float*)d_in[13];
  const float* W_out  = (const float*)d_in[14];
  const float* b_out  = (const float*)d_in[15];

  float* ws = (float*)d_ws;
  // ---- workspace map (float offsets), phase-disjoint ----
  // R0 [0, 4,718,592)
  u16*   qkvbf       = (u16*)ws;                    // ph1-2
  u16*   enh_bf      = (u16*)ws;                    // ph7
  u16*   crossqbf    = (u16*)(ws + 1572864);        // ph5-6
  u16*   crossattn_bf= (u16*)(ws + 3145728);        // ph6-7
  // R1 [4,718,592, 13,107,200)
  float* R1 = ws + 4718592;
  u16*   hs_bf   = (u16*)R1;                        // ph1 (dead after QKV)
  u16*   wqkvt1  = (u16*)(R1 + 1572864);            // ph1
  u16*   VT      = (u16*)R1;                        // ph2: 3,145,728 u16 (overwrites hs_bf)
  u16*   amh     = (u16*)(R1 + 4194304);            // ph2: bf16 am partial (half1), 8.4M u16
  float* projbuf = R1;                              // ph3
  float* Snode   = R1;                              // ph4 (393,216)
  u16*   wqkvt2  = (u16*)(R1 + 4000000);            // ph4
  u16*   wot     = (u16*)(R1 + 6291456);            // ph3-4
  u16*   wqkvc   = (u16*)R1;                        // ph5
  u16*   woc     = (u16*)(R1 + 6291456);            // ph5-7
  u16*   wout    = (u16*)(R1 + 6586368);            // ph5-7
  float* Scross  = R1;                              // ph6 (6,291,456)
  float* crossproj = R1;                              // ph7
  // R2 [13,107,200, 16,252,928)
  float* R2 = ws + 13107200;
  u16*   attnout_bf = (u16*)R2;                     // ph2-3a (bf16 attn out, direct)
  u16*   tokout_bf  = (u16*)R2;                     // ph3b-5 (after gemm ph3 consumed attnout)
  float* wvec       = R2 + 1572864;
  float* colpart    = R2 + 1576960;
  float* nodepre    = R2 + 1609728;
  float* nodeproj   = R2 + 1806336;
  u16*   nodepre_bf = (u16*)(R2 + 2002944);
  u16*   nodeattn_bf= (u16*)(R2 + 2101248);
  u16*   nodeemb_bf = (u16*)(R2 + 2199552);
  u16*   nodeqkvbf  = (u16*)(R2 + 2297856);
  u16*   crosskvbf  = (u16*)(R2 + 2592768);
  // R3
  float* tokout = ws + 16252928;

  float* outp       = (float*)d_out;
  float* o_output   = outp;
  float* o_nodeemb  = outp + 3145728;
  float* o_tokattn  = o_nodeemb + 196608;
  float* o_nodeattn = o_tokattn + 8388608;
  float* o_crossw   = o_nodeattn + 32768;

  // ---- ph1: convert + token QKV ----
  conv_bf16<<<1536, 256, 0, stream>>>(hs, hs_bf, 393216);
  conv_bf16<<<864, 256, 0, stream>>>(Wqkv_t, wqkvt1, 221184);
  gemm_bf16<1><<<dim3(18, 32), 256, 0, stream>>>(hs_bf, 768, wqkvt1, 768, bqkv_t, qkvbf, 2304, 768);

  // ---- ph2: fused token self-attention (QBLK=32, XCD-local) ----
  transpose_v<<<dim3(32, 24), 256, 0, stream>>>(qkvbf, VT);
  fused_tok_attn<<<256, 512, 0, stream>>>(qkvbf, VT, o_tokattn, amh, attnout_bf);
  combine_am<<<4096, 256, 0, stream>>>(o_tokattn, amh);

  // ---- ph3: token out projection + LN ----
  conv_bf16<<<288, 256, 0, stream>>>(Wo_t, wot, 73728);
  gemm_bf16<0><<<dim3(6, 32), 256, 0, stream>>>(attnout_bf, 768, wot, 768, bo_t, projbuf, 768, 768);
  ln_kernel<<<4096, 256, 0, stream>>>(hs, projbuf, g_tok, b_tok, tokout, tokout_bf);

  // ---- ph4: token->node aggregation + node attention ----
  colmean_part<<<dim3(8, 2, 8), 256, 0, stream>>>(o_tokattn, colpart);
  colmean_final<<<dim3(8, 2), 256, 0, stream>>>(colpart, wvec);
  aggregate_kernel<<<dim3(128, 2), 256, 0, stream>>>(tokout, wvec, t2s, nodepre, nodepre_bf);
  conv_bf16<<<864, 256, 0, stream>>>(Wqkv_t, wqkvt2, 221184);
  gemm_bf16<1><<<dim3(18, 2), 256, 0, stream>>>(nodepre_bf, 768, wqkvt2, 768, bqkv_t, nodeqkvbf, 2304, 768);
  qk_mfma<<<dim3(1, 1, 24), 256, 0, stream>>>(
      nodeqkvbf, 2304, (long)128 * 2304, nodeqkvbf + 768, 2304, (long)128 * 2304,
      Snode, 16384, 128, 12, 0.125f);
  softmax_small<<<dim3(128, 2), 128, 0, stream>>>(Snode, o_nodeattn, 128);
  pv_small<<<dim3(1, 24), 256, 0, stream>>>(
      (const u16*)Snode, 32768, nodeqkvbf, 2304, (long)128 * 2304, 1536,
      nodeattn_bf, (long)128 * 768);
  gemm_bf16<0><<<dim3(6, 2), 256, 0, stream>>>(nodeattn_bf, 768, wot, 768, bo_t, nodeproj, 768, 768);
  ln_kernel<<<256, 256, 0, stream>>>(nodepre, nodeproj, g_node, b_node, o_nodeemb, nodeemb_bf);

  // ---- ph5: cross projections ----
  conv_bf16<<<864, 256, 0, stream>>>(Wqkv_c, wqkvc, 221184);
  conv_bf16<<<288, 256, 0, stream>>>(Wo_c, woc, 73728);
  conv_bf16<<<288, 256, 0, stream>>>(W_out, wout, 73728);
  gemm_bf16<1><<<dim3(6, 32), 256, 0, stream>>>(tokout_bf, 768, wqkvc, 768, bqkv_c, crossqbf, 768, 768);
  gemm_bf16<1><<<dim3(12, 2), 256, 0, stream>>>(nodeemb_bf, 768, wqkvc + 768 * 768, 768, bqkv_c + 768,
                                                crosskvbf, 1536, 768);

  // ---- ph6: cross attention (24 planes) ----
  qk_mfma<<<dim3(1, 16, 24), 256, 0, stream>>>(
      crossqbf, 768, (long)2048 * 768, crosskvbf, 1536, (long)128 * 1536,
      Scross, 262144, 128, 12, 0.125f);
  softmax_small<<<dim3(2048, 2), 128, 0, stream>>>(Scross, o_crossw, 2048);
  pv_small<<<dim3(16, 24), 256, 0, stream>>>(
      (const u16*)Scross, 524288, crosskvbf, 1536, (long)128 * 1536, 768,
      crossattn_bf, (long)2048 * 768);

  // ---- ph7: cross out projection, combine, final ----
  gemm_bf16<0><<<dim3(6, 32), 256, 0, stream>>>(crossattn_bf, 768, woc, 768, bo_c, crossproj, 768, 768);
  enhanced_kernel<<<1536, 256, 0, stream>>>(tokout, crossproj, o_nodeemb, t2s, enh_bf);
  gemm_bf16<0><<<dim3(6, 32), 256, 0, stream>>>(enh_bf, 768, wout, 768, b_out, o_output, 768, 768);
}

// Round 10
// 552.761 us; speedup vs baseline: 1.0097x; 1.0097x over previous
//
#include <hip/hip_runtime.h>
#include <cstdint>

#define B_ 2
#define S_ 2048
#define D_ 768
#define H_ 12
#define DH_ 64
#define N_ 128

typedef unsigned short u16;
typedef unsigned int u32;
typedef unsigned long long u64;
typedef __attribute__((ext_vector_type(8))) short short8;
typedef __attribute__((ext_vector_type(4))) float f32x4;

#define MFMA16(a, b, c) __builtin_amdgcn_mfma_f32_16x16x32_bf16(a, b, c, 0, 0, 0)

__device__ inline u16 f2bf(float f) {
  union { float f; u32 u; } v; v.f = f;
  u32 r = v.u + 0x7FFFu + ((v.u >> 16) & 1u);
  return (u16)(r >> 16);
}
__device__ inline u32 pk2(float a, float b) {
  return (u32)f2bf(a) | ((u32)f2bf(b) << 16);
}
// HW packed f32->bf16 (RNE), lo=src0 hi=src1: 1 instr replaces ~9 VALU
__device__ inline u32 cvtpk(float lo, float hi) {
  u32 r;
  asm("v_cvt_pk_bf16_f32 %0, %1, %2" : "=v"(r) : "v"(lo), "v"(hi));
  return r;
}
__device__ inline float bf2f(u16 h) {
  union { u32 u; float f; } v; v.u = ((u32)h) << 16;
  return v.f;
}
__device__ inline float wredsum(float v) {
  #pragma unroll
  for (int o = 32; o > 0; o >>= 1) v += __shfl_down(v, o);
  return v;
}
__device__ inline void async_lds16(const u16* g, u16* l) {
  __builtin_amdgcn_global_load_lds((const __attribute__((address_space(1))) void*)g,
                                   (__attribute__((address_space(3))) void*)l, 16, 0, 0);
}

// ---------------- fp32 -> bf16 conversion, 8 elems/thread ----------------
__global__ void conv_bf16(const float* __restrict__ in, u16* __restrict__ outp, int n8) {
  int i = blockIdx.x * 256 + threadIdx.x;
  if (i >= n8) return;
  const float4* p = (const float4*)(in + (size_t)i * 8);
  float4 a = p[0], b = p[1];
  uint4 u;
  u.x = pk2(a.x, a.y); u.y = pk2(a.z, a.w); u.z = pk2(b.x, b.y); u.w = pk2(b.z, b.w);
  *(uint4*)(outp + (size_t)i * 8) = u;
}

// ================= pure-bf16 MFMA GEMM: C = A[M,K] @ W[N,K]^T + bias =================
template <int OUT_BF16>
__global__ __launch_bounds__(256) void gemm_bf16(
    const u16* __restrict__ A, int lda,
    const u16* __restrict__ W, int ldb,
    const float* __restrict__ bias,
    void* __restrict__ Cout, int ldc, int K) {
  __shared__ u16 As[128 * 32];
  __shared__ u16 Ws[128 * 32];
  const int tid = threadIdx.x;
  const int m0 = blockIdx.y * 128, n0 = blockIdx.x * 128;
  const int w = tid >> 6, lane = tid & 63;
  const int msub = (w & 1) * 64, nsub = (w >> 1) * 64;
  const int lrow = lane & 15, quad = lane >> 4;
  const int e0 = tid * 8;
  const int r0 = e0 >> 5, c0 = e0 & 31;
  const int e1 = e0 + 2048;
  const int r1 = e1 >> 5, c1 = e1 & 31;
  const u16* Ag0 = A + (size_t)(m0 + r0) * lda + c0;
  const u16* Ag1 = A + (size_t)(m0 + r1) * lda + c1;
  const u16* Wg0 = W + (size_t)(n0 + r0) * ldb + c0;
  const u16* Wg1 = W + (size_t)(n0 + r1) * ldb + c1;
  u16* AsB0 = As + (w << 9);
  u16* AsB1 = As + 2048 + (w << 9);
  u16* WsB0 = Ws + (w << 9);
  u16* WsB1 = Ws + 2048 + (w << 9);
  f32x4 zero = {0.f, 0.f, 0.f, 0.f};
  f32x4 acc[4][4];
  #pragma unroll
  for (int i = 0; i < 4; i++)
    #pragma unroll
    for (int j = 0; j < 4; j++) acc[i][j] = zero;
  for (int k0 = 0; k0 < K; k0 += 32) {
    __syncthreads();
    async_lds16(Ag0 + k0, AsB0);
    async_lds16(Ag1 + k0, AsB1);
    async_lds16(Wg0 + k0, WsB0);
    async_lds16(Wg1 + k0, WsB1);
    __syncthreads();
    short8 af[4], bf[4];
    #pragma unroll
    for (int i = 0; i < 4; i++)
      af[i] = *(const short8*)(As + (msub + i * 16 + lrow) * 32 + quad * 8);
    #pragma unroll
    for (int j = 0; j < 4; j++)
      bf[j] = *(const short8*)(Ws + (nsub + j * 16 + lrow) * 32 + quad * 8);
    #pragma unroll
    for (int i = 0; i < 4; i++)
      #pragma unroll
      for (int j = 0; j < 4; j++)
        acc[i][j] = MFMA16(af[i], bf[j], acc[i][j]);
  }
  #pragma unroll
  for (int i = 0; i < 4; i++) {
    #pragma unroll
    for (int j = 0; j < 4; j++) {
      int col = n0 + nsub + j * 16 + lrow;
      float bv = bias ? bias[col] : 0.f;
      #pragma unroll
      for (int r = 0; r < 4; r++) {
        int row = m0 + msub + i * 16 + quad * 4 + r;
        float val = acc[i][j][r] + bv;
        if (OUT_BF16) ((u16*)Cout)[(size_t)row * ldc + col] = f2bf(val);
        else ((float*)Cout)[(size_t)row * ldc + col] = val;
      }
    }
  }
}

// ================= V transpose: VT[b*12+h][d][s] = qkv[b][s][1536+h*64+d] =================
__global__ __launch_bounds__(256) void transpose_v(const u16* __restrict__ qkv, u16* __restrict__ VT) {
  __shared__ u16 t[64][72];
  const int z = blockIdx.y, b = z / 12, h = z - b * 12;
  const int s0 = blockIdx.x * 64;
  const int tid = threadIdx.x;
  {
    int r = tid >> 2, dp = (tid & 3) * 16;
    const u16* src = qkv + (size_t)b * 2048 * 2304 + (size_t)(s0 + r) * 2304 + 1536 + h * 64 + dp;
    *(uint4*)&t[r][dp] = *(const uint4*)src;
    *(uint4*)&t[r][dp + 8] = *(const uint4*)(src + 8);
  }
  __syncthreads();
  int d = tid >> 2, sp = (tid & 3) * 16;
  u16 vals[16];
  #pragma unroll
  for (int i = 0; i < 16; i++) vals[i] = t[sp + i][d];
  u16* dst = VT + ((size_t)z * 64 + d) * 2048 + s0 + sp;
  *(uint4*)dst = *(uint4*)&vals[0];
  *(uint4*)(dst + 8) = *(uint4*)&vals[8];
}

// ================= fused token attention (v10: QBLK=32, XCD-local) ====================
__global__ __launch_bounds__(512, 2) void fused_tok_attn(
    const u16* __restrict__ qkv, const u16* __restrict__ VT,
    float* __restrict__ amF, u16* __restrict__ amH, u16* __restrict__ attnout) {
  __shared__ u16 pbuf[8 * 2 * 16 * 264];   // [wave][qsub][q=lrow][s-local 0..256)
  __shared__ float lred[8][2][16];
  __shared__ float obuf[2][2][16][66];     // [qsub][s-half][q][d]
  const int tid = threadIdx.x;
  const int w = tid >> 6, lane = tid & 63;
  const int lrow = lane & 15, quad = lane >> 4;
  // ---- XCD-aware decode: combo (b,z) -> XCD pair {2c, 2c+1} ----
  const int lid = blockIdx.x;
  const int xcd = lid & 7;
  const int combo = xcd >> 1;
  const int b = combo >> 1, z = combo & 1;
  const int q0 = (((lid >> 3) << 1) + (xcd & 1)) << 5;   // 32-row tile
  const int h0 = z * 6;
  const u16* qp = qkv + (size_t)b * 2048 * 2304;
  const u16* kp = qp + 768;
  const int strip = w * 256;               // pass-A ownership
  const int jj = w & 3, sh = w >> 2;       // pass-C ownership
  u16* ob = attnout + (size_t)b * 2048 * 768 + (size_t)q0 * 768;
  u16* pbA = pbuf + (w * 2 + 0) * 16 * 264;
  u16* pbB = pbuf + (w * 2 + 1) * 16 * 264;
  f32x4 zero = {0.f, 0.f, 0.f, 0.f};
  float amreg[2][8][8];
  #pragma unroll
  for (int g = 0; g < 2; g++)
    #pragma unroll
    for (int c = 0; c < 8; c++)
      #pragma unroll
      for (int e = 0; e < 8; e++) amreg[g][c][e] = 0.f;
  for (int hh = 0; hh < 6; hh++) {
    const int h = h0 + hh;
    const u16* qhA = qp + (size_t)(q0 + lrow) * 2304 + h * 64 + quad * 8;
    const u16* qhB = qp + (size_t)(q0 + 16 + lrow) * 2304 + h * 64 + quad * 8;
    short8 qfA0 = *(const short8*)qhA;
    short8 qfA1 = *(const short8*)(qhA + 32);
    short8 qfB0 = *(const short8*)qhB;
    short8 qfB1 = *(const short8*)(qhB + 32);
    // ---- pass A: S^T = mfma(K,Q) for BOTH q-subs off shared K loads ----
    float lsumA = 0.f, lsumB = 0.f;
    #pragma unroll
    for (int t = 0; t < 16; t++) {
      const u16* kh = kp + (size_t)(strip + t * 16 + lrow) * 2304 + h * 64 + quad * 8;
      short8 kf0 = *(const short8*)kh;
      short8 kf1 = *(const short8*)(kh + 32);
      f32x4 svA = zero, svB = zero;
      svA = MFMA16(kf0, qfA0, svA);   // D[s][q]: lane -> q=lrow, s=t*16+quad*4+r
      svA = MFMA16(kf1, qfA1, svA);
      svB = MFMA16(kf0, qfB0, svB);
      svB = MFMA16(kf1, qfB1, svB);
      float a0 = __expf(svA[0] * 0.125f);
      float a1 = __expf(svA[1] * 0.125f);
      float a2 = __expf(svA[2] * 0.125f);
      float a3 = __expf(svA[3] * 0.125f);
      float b0 = __expf(svB[0] * 0.125f);
      float b1 = __expf(svB[1] * 0.125f);
      float b2 = __expf(svB[2] * 0.125f);
      float b3 = __expf(svB[3] * 0.125f);
      lsumA += (a0 + a1) + (a2 + a3);
      lsumB += (b0 + b1) + (b2 + b3);
      u32 wA0 = cvtpk(a0, a1), wA1 = cvtpk(a2, a3);
      u32 wB0 = cvtpk(b0, b1), wB1 = cvtpk(b2, b3);
      *(u64*)(pbA + lrow * 264 + t * 16 + quad * 4) = (u64)wA0 | ((u64)wA1 << 32);
      *(u64*)(pbB + lrow * 264 + t * 16 + quad * 4) = (u64)wB0 | ((u64)wB1 << 32);
    }
    lsumA += __shfl_xor(lsumA, 16);
    lsumA += __shfl_xor(lsumA, 32);
    lsumB += __shfl_xor(lsumB, 16);
    lsumB += __shfl_xor(lsumB, 32);
    if (lane < 16) { lred[w][0][lane] = lsumA; lred[w][1][lane] = lsumB; }
    __syncthreads();  // barrier1: pbuf + lred visible to all waves
    float invqA, invqB;
    float inv4A[4], inv4B[4];
    {
      float sA = 0.f, sB = 0.f;
      #pragma unroll
      for (int w2 = 0; w2 < 8; w2++) { sA += lred[w2][0][lrow]; sB += lred[w2][1][lrow]; }
      invqA = 1.f / sA; invqB = 1.f / sB;
      #pragma unroll
      for (int r = 0; r < 4; r++) {
        float rA = 0.f, rB = 0.f;
        #pragma unroll
        for (int w2 = 0; w2 < 8; w2++) {
          rA += lred[w2][0][quad * 4 + r];
          rB += lred[w2][1][quad * 4 + r];
        }
        inv4A[r] = 1.f / rA; inv4B[r] = 1.f / rB;
      }
    }
    // ---- am accumulate from own strip's bf16 P (both q-subs) ----
    #pragma unroll
    for (int c = 0; c < 8; c++) {
      short8 pfa = *(const short8*)(pbA + lrow * 264 + c * 32 + quad * 8);
      short8 pfb = *(const short8*)(pbB + lrow * 264 + c * 32 + quad * 8);
      #pragma unroll
      for (int e = 0; e < 8; e++) {
        amreg[0][c][e] += bf2f((u16)pfa[e]) * invqA;
        amreg[1][c][e] += bf2f((u16)pfb[e]) * invqB;
      }
    }
    // ---- pass C: wave owns (d-quarter jj, s-half sh) for BOTH q-subs ----
    f32x4 oA = zero, oB = zero;
    {
      const u16* vtp = VT + (size_t)(b * 12 + h) * 64 * 2048;
      const u16* vbase = vtp + (size_t)(jj * 16 + lrow) * 2048 + sh * 1024 + quad * 8;
      #pragma unroll
      for (int cc = 0; cc < 32; cc++) {
        short8 vf = *(const short8*)(vbase + cc * 32);
        const u16* pba = pbuf + (((4 * sh + (cc >> 3)) * 2 + 0) * 16 * 264) + lrow * 264 + (cc & 7) * 32 + quad * 8;
        const u16* pbb = pba + 16 * 264;
        oA = MFMA16(*(const short8*)pba, vf, oA);
        oB = MFMA16(*(const short8*)pbb, vf, oB);
      }
    }
    #pragma unroll
    for (int r = 0; r < 4; r++) {
      obuf[0][sh][quad * 4 + r][jj * 16 + lrow] = oA[r] * inv4A[r];
      obuf[1][sh][quad * 4 + r][jj * 16 + lrow] = oB[r] * inv4B[r];
    }
    __syncthreads();  // barrier2: obuf complete; pbuf reads done -> safe to rewrite
    #pragma unroll
    for (int ee = 0; ee < 4; ee++) {
      int e2 = tid + ee * 512;
      int row = e2 >> 6, col = e2 & 63;
      int g = row >> 4, rr = row & 15;
      float s = obuf[g][0][rr][col] + obuf[g][1][rr][col];
      ob[(size_t)row * 768 + h * 64 + col] = f2bf(s);
    }
  }
  // ---- am partial write (raw sums over this half's 6 heads) ----
  if (z == 0) {
    #pragma unroll
    for (int g = 0; g < 2; g++) {
      float* ar = amF + ((size_t)b * 2048 + q0 + g * 16 + lrow) * 2048 + strip;
      #pragma unroll
      for (int c = 0; c < 8; c++) {
        float4 v0 = {amreg[g][c][0], amreg[g][c][1], amreg[g][c][2], amreg[g][c][3]};
        float4 v1 = {amreg[g][c][4], amreg[g][c][5], amreg[g][c][6], amreg[g][c][7]};
        *(float4*)(ar + c * 32 + quad * 8) = v0;
        *(float4*)(ar + c * 32 + quad * 8 + 4) = v1;
      }
    }
  } else {
    #pragma unroll
    for (int g = 0; g < 2; g++) {
      u16* ar = amH + ((size_t)b * 2048 + q0 + g * 16 + lrow) * 2048 + strip;
      #pragma unroll
      for (int c = 0; c < 8; c++) {
        uint4 u;
        u.x = pk2(amreg[g][c][0], amreg[g][c][1]);
        u.y = pk2(amreg[g][c][2], amreg[g][c][3]);
        u.z = pk2(amreg[g][c][4], amreg[g][c][5]);
        u.w = pk2(amreg[g][c][6], amreg[g][c][7]);
        *(uint4*)(ar + c * 32 + quad * 8) = u;
      }
    }
  }
}

// ================= fused small attention (Sk=128): node + cross =======================
// Replaces qk_mfma + softmax_small + pv_small. Per block: 16 q rows, one batch;
// loops all 12 heads. Swapped QK^T (lane owns q=lrow) -> softmax = 2 shfl + tiny
// LDS reduce; P (unnormalized bf16) -> pbuf; PV = mfma(P, V^T) with V^T staged in
// LDS; normalization folded into epilogue. Head-mean attn accumulated in 8 regs,
// written once (wout). No score tensor ever touches global memory.
__global__ __launch_bounds__(256) void attn_small(
    const u16* __restrict__ Qp, int ldq, long qbs,
    const u16* __restrict__ Kp, int ldk, long kbs,
    const u16* __restrict__ Vp,
    u16* __restrict__ Outb, long obs,
    float* __restrict__ wout, int Sq) {
  __shared__ u16 pbuf[16][136];   // P[q][s 0..128)
  __shared__ u16 Vs[64][136];     // V^T[d][s]
  __shared__ float lred[4][16];
  const int tid = threadIdx.x;
  const int w = tid >> 6, lane = tid & 63;
  const int lrow = lane & 15, quad = lane >> 4;
  const int q0 = blockIdx.x * 16, b = blockIdx.y;
  const u16* qb = Qp + (size_t)b * qbs;
  const u16* kb = Kp + (size_t)b * kbs;
  const u16* vb = Vp + (size_t)b * kbs;
  u16* ob = Outb + (size_t)b * obs + (size_t)q0 * 768;
  f32x4 zero = {0.f, 0.f, 0.f, 0.f};
  float cw[2][4];   // head-mean attn: [t][r] -> s = w*32 + t*16 + quad*4 + r, q = lrow
  #pragma unroll
  for (int t = 0; t < 2; t++)
    #pragma unroll
    for (int r = 0; r < 4; r++) cw[t][r] = 0.f;
  for (int h = 0; h < 12; h++) {
    __syncthreads();  // WAR: prev head's Vs/pbuf/lred reads done
    // ---- stage V^T (V[s][h*64+d] -> Vs[d][s]), 4 uint4 loads / thread ----
    #pragma unroll
    for (int j = 0; j < 4; j++) {
      int lin = tid * 32 + j * 8;
      int s = lin >> 6, d = lin & 63;
      uint4 vv = *(const uint4*)(vb + (size_t)s * ldk + h * 64 + d);
      const u16* vsrc = (const u16*)&vv;
      #pragma unroll
      for (int u = 0; u < 8; u++) Vs[d + u][s] = vsrc[u];
    }
    // ---- pass A: S^T = mfma(K,Q); lane -> q=lrow, s = w*32 + t*16 + quad*4 + r ----
    const u16* qh = qb + (size_t)(q0 + lrow) * ldq + h * 64 + quad * 8;
    short8 qf0 = *(const short8*)qh;
    short8 qf1 = *(const short8*)(qh + 32);
    float pr[2][4];
    float lsum = 0.f;
    #pragma unroll
    for (int t = 0; t < 2; t++) {
      const u16* kh = kb + (size_t)(w * 32 + t * 16 + lrow) * ldk + h * 64 + quad * 8;
      short8 kf0 = *(const short8*)kh;
      short8 kf1 = *(const short8*)(kh + 32);
      f32x4 sv = zero;
      sv = MFMA16(kf0, qf0, sv);
      sv = MFMA16(kf1, qf1, sv);
      #pragma unroll
      for (int r = 0; r < 4; r++) {
        float p = __expf(sv[r] * 0.125f);
        pr[t][r] = p;
        lsum += p;
      }
      u32 w0 = cvtpk(pr[t][0], pr[t][1]), w1 = cvtpk(pr[t][2], pr[t][3]);
      *(u64*)(&pbuf[lrow][w * 32 + t * 16 + quad * 4]) = (u64)w0 | ((u64)w1 << 32);
    }
    lsum += __shfl_xor(lsum, 16);
    lsum += __shfl_xor(lsum, 32);
    if (lane < 16) lred[w][lane] = lsum;
    __syncthreads();  // pbuf + lred + Vs complete
    float invq = 1.f / (lred[0][lrow] + lred[1][lrow] + lred[2][lrow] + lred[3][lrow]);
    float inv4[4];
    #pragma unroll
    for (int r = 0; r < 4; r++)
      inv4[r] = 1.f / (lred[0][quad * 4 + r] + lred[1][quad * 4 + r] +
                       lred[2][quad * 4 + r] + lred[3][quad * 4 + r]);
    // ---- head-mean attn accumulate (raw exp * invq) ----
    #pragma unroll
    for (int t = 0; t < 2; t++)
      #pragma unroll
      for (int r = 0; r < 4; r++) cw[t][r] += pr[t][r] * invq;
    // ---- pass C: wave owns d-block w (16 dims); O = P @ V^T ----
    f32x4 oacc = zero;
    #pragma unroll
    for (int cc = 0; cc < 4; cc++) {
      short8 pf = *(const short8*)(&pbuf[lrow][cc * 32 + quad * 8]);
      short8 vf = *(const short8*)(&Vs[w * 16 + lrow][cc * 32 + quad * 8]);
      oacc = MFMA16(pf, vf, oacc);
    }
    // D[row=q=quad*4+r][col=d=lrow]
    #pragma unroll
    for (int r = 0; r < 4; r++)
      ob[(size_t)(quad * 4 + r) * 768 + h * 64 + w * 16 + lrow] = f2bf(oacc[r] * inv4[r]);
  }
  // ---- head-mean write: wout[b][q0+lrow][w*32 + t*16 + quad*4 + r] ----
  float* wr = wout + ((size_t)b * Sq + q0 + lrow) * 128 + w * 32;
  const float c12 = 1.f / 12.f;
  #pragma unroll
  for (int t = 0; t < 2; t++)
    #pragma unroll
    for (int r = 0; r < 4; r++)
      wr[t * 16 + quad * 4 + r] = cw[t][r] * c12;
}

// ======= colmean_part + combine_am fused: o_tokattn = (amF + bf16(amH))/12, col-sum ====
// NOTE: must run BEFORE ph3 (conv_bf16 of Wo_t writes into R1 range that aliases amh).
__global__ void colmean_part(float* __restrict__ amF, const u16* __restrict__ amH,
                             float* __restrict__ part) {
  int b = blockIdx.y, z = blockIdx.z;
  int k = blockIdx.x * 256 + threadIdx.x;
  float* p = amF + (size_t)b * S_ * S_ + (size_t)z * 256 * S_ + k;
  const u16* hp = amH + (size_t)b * S_ * S_ + (size_t)z * 256 * S_ + k;
  const float c12 = 1.f / 12.f;
  float s = 0.f;
  #pragma unroll 8
  for (int q = 0; q < 256; q++) {
    float v = (p[(size_t)q * S_] + bf2f(hp[(size_t)q * S_])) * c12;
    p[(size_t)q * S_] = v;
    s += v;
  }
  part[((size_t)z * B_ + b) * S_ + k] = s;
}

__global__ void colmean_final(const float* __restrict__ part, float* __restrict__ w) {
  int b = blockIdx.y;
  int k = blockIdx.x * 256 + threadIdx.x;
  float s = 0.f;
  #pragma unroll
  for (int z = 0; z < 8; z++) s += part[((size_t)z * B_ + b) * S_ + k];
  w[b * S_ + k] = s * (1.f / (float)S_);
}

// ================= LayerNorm of (x1 + x2) with optional bf16 twin =================
__global__ void ln_kernel(const float* __restrict__ x1, const float* __restrict__ x2,
                          const float* __restrict__ g, const float* __restrict__ bt,
                          float* __restrict__ outp, u16* __restrict__ outbf) {
  const int row = blockIdx.x;
  const int tid = threadIdx.x;
  __shared__ float red[8];
  float v[3];
  #pragma unroll
  for (int j = 0; j < 3; j++) {
    int c = tid + j * 256;
    v[j] = x1[(size_t)row * D_ + c] + x2[(size_t)row * D_ + c];
  }
  float s = v[0] + v[1] + v[2];
  s = wredsum(s);
  int wid = tid >> 6, lane = tid & 63;
  if (lane == 0) red[wid] = s;
  __syncthreads();
  float mean = (red[0] + red[1] + red[2] + red[3]) / 768.f;
  float d0 = v[0] - mean, d1 = v[1] - mean, d2 = v[2] - mean;
  float q = d0 * d0 + d1 * d1 + d2 * d2;
  q = wredsum(q);
  if (lane == 0) red[4 + wid] = q;
  __syncthreads();
  float var = (red[4] + red[5] + red[6] + red[7]) / 768.f;
  float inv = rsqrtf(var + 1e-5f);
  #pragma unroll
  for (int j = 0; j < 3; j++) {
    int c = tid + j * 256;
    float val = (v[j] - mean) * inv * g[c] + bt[c];
    outp[(size_t)row * D_ + c] = val;
    if (outbf) outbf[(size_t)row * D_ + c] = f2bf(val);
  }
}

// ================= segment aggregation (seg sorted per batch) =================
__global__ void aggregate_kernel(const float* __restrict__ x, const float* __restrict__ w,
                                 const int* __restrict__ seg, float* __restrict__ outp,
                                 u16* __restrict__ outbf) {
  const int b = blockIdx.y, n = blockIdx.x;
  const int* sg = seg + b * S_;
  int l = 0, rr = S_;
  while (l < rr) { int mid = (l + rr) >> 1; if (sg[mid] < n) l = mid + 1; else rr = mid; }
  const int lo = l;
  rr = S_;
  while (l < rr) { int mid = (l + rr) >> 1; if (sg[mid] < n + 1) l = mid + 1; else rr = mid; }
  const int hi = l;
  const int tid = threadIdx.x;
  float acc[3] = {0.f, 0.f, 0.f};
  float den = 0.f;
  for (int s = lo; s < hi; s++) {
    float ww = w[b * S_ + s];
    den += ww;
    const float* xr = x + (size_t)(b * S_ + s) * D_;
    #pragma unroll
    for (int j = 0; j < 3; j++) acc[j] += ww * xr[tid + j * 256];
  }
  float invd = 1.f / (den + 1e-8f);
  size_t ro = (size_t)(b * N_ + n) * D_;
  #pragma unroll
  for (int j = 0; j < 3; j++) {
    float val = acc[j] * invd;
    outp[ro + tid + j * 256] = val;
    outbf[ro + tid + j * 256] = f2bf(val);
  }
}

// ================= enhanced = tokout + cross_proj + gather(node_emb), bf16 out ==========
__global__ void enhanced_kernel(const float* __restrict__ tokout, const float* __restrict__ crossp,
                                const float* __restrict__ nodeemb, const int* __restrict__ seg,
                                u16* __restrict__ outbf) {
  int g8 = blockIdx.x * 256 + threadIdx.x;
  int bs = g8 / 96, d0 = (g8 - bs * 96) * 8;
  int b = bs >> 11;
  int n = seg[bs];
  const float* t = tokout + (size_t)bs * D_ + d0;
  const float* cp = crossp + (size_t)bs * D_ + d0;
  const float* ne = nodeemb + (size_t)(b * N_ + n) * D_ + d0;
  float4 a0 = *(const float4*)t, a1 = *(const float4*)(t + 4);
  float4 b0 = *(const float4*)cp, b1 = *(const float4*)(cp + 4);
  float4 c0 = *(const float4*)ne, c1 = *(const float4*)(ne + 4);
  uint4 u;
  u.x = pk2(a0.x + b0.x + c0.x, a0.y + b0.y + c0.y);
  u.y = pk2(a0.z + b0.z + c0.z, a0.w + b0.w + c0.w);
  u.z = pk2(a1.x + b1.x + c1.x, a1.y + b1.y + c1.y);
  u.w = pk2(a1.z + b1.z + c1.z, a1.w + b1.w + c1.w);
  *(uint4*)(outbf + (size_t)g8 * 8) = u;
}

extern "C" void kernel_launch(void* const* d_in, const int* in_sizes, int n_in,
                              void* d_out, int out_size, void* d_ws, size_t ws_size,
                              hipStream_t stream) {
  const float* hs     = (const float*)d_in[0];
  const int*   t2s    = (const int*)d_in[1];
  const float* Wqkv_t = (const float*)d_in[2];
  const float* bqkv_t = (const float*)d_in[3];
  const float* Wo_t   = (const float*)d_in[4];
  const float* bo_t   = (const float*)d_in[5];
  const float* Wqkv_c = (const float*)d_in[6];
  const float* bqkv_c = (const float*)d_in[7];
  const float* Wo_c   = (const float*)d_in[8];
  const float* bo_c   = (const float*)d_in[9];
  const float* g_tok  = (const float*)d_in[10];
  const float* b_tok  = (const float*)d_in[11];
  const float* g_node = (const float*)d_in[12];
  const float* b_node = (const float*)d_in[13];
  const float* W_out  = (const float*)d_in[14];
  const float* b_out  = (const float*)d_in[15];

  float* ws = (float*)d_ws;
  // ---- workspace map (float offsets), phase-disjoint ----
  // R0 [0, 4,718,592)
  u16*   qkvbf       = (u16*)ws;                    // ph1-2
  u16*   enh_bf      = (u16*)ws;                    // ph7
  u16*   crossqbf    = (u16*)(ws + 1572864);        // ph5-6
  u16*   crossattn_bf= (u16*)(ws + 3145728);        // ph6-7
  // R1 [4,718,592, 13,107,200)
  float* R1 = ws + 4718592;
  u16*   hs_bf   = (u16*)R1;                        // ph1 (dead after QKV)
  u16*   wqkvt1  = (u16*)(R1 + 1572864);            // ph1
  u16*   VT      = (u16*)R1;                        // ph2: 3,145,728 u16 (overwrites hs_bf)
  u16*   amh     = (u16*)(R1 + 4194304);            // ph2 only: consumed by colmean_part BEFORE ph3
  float* projbuf = R1;                              // ph3
  u16*   wqkvt2  = (u16*)(R1 + 4000000);            // ph4
  u16*   wot     = (u16*)(R1 + 6291456);            // ph3-4 (aliases amh range -> amh must be dead)
  u16*   wqkvc   = (u16*)R1;                        // ph5
  u16*   woc     = (u16*)(R1 + 6291456);            // ph5-7
  u16*   wout    = (u16*)(R1 + 6586368);            // ph5-7
  float* crossproj = R1;                            // ph7
  // R2 [13,107,200, 16,252,928)
  float* R2 = ws + 13107200;
  u16*   attnout_bf = (u16*)R2;                     // ph2-3a (bf16 attn out, direct)
  u16*   tokout_bf  = (u16*)R2;                     // ph3b-5 (after gemm ph3 consumed attnout)
  float* wvec       = R2 + 1572864;
  float* colpart    = R2 + 1576960;
  float* nodepre    = R2 + 1609728;
  float* nodeproj   = R2 + 1806336;
  u16*   nodepre_bf = (u16*)(R2 + 2002944);
  u16*   nodeattn_bf= (u16*)(R2 + 2101248);
  u16*   nodeemb_bf = (u16*)(R2 + 2199552);
  u16*   nodeqkvbf  = (u16*)(R2 + 2297856);
  u16*   crosskvbf  = (u16*)(R2 + 2592768);
  // R3
  float* tokout = ws + 16252928;

  float* outp       = (float*)d_out;
  float* o_output   = outp;
  float* o_nodeemb  = outp + 3145728;
  float* o_tokattn  = o_nodeemb + 196608;
  float* o_nodeattn = o_tokattn + 8388608;
  float* o_crossw   = o_nodeattn + 32768;

  // ---- ph1: convert + token QKV ----
  conv_bf16<<<1536, 256, 0, stream>>>(hs, hs_bf, 393216);
  conv_bf16<<<864, 256, 0, stream>>>(Wqkv_t, wqkvt1, 221184);
  gemm_bf16<1><<<dim3(18, 32), 256, 0, stream>>>(hs_bf, 768, wqkvt1, 768, bqkv_t, qkvbf, 2304, 768);

  // ---- ph2: fused token self-attention + am combine/col-sum (amh consumed HERE) ----
  transpose_v<<<dim3(32, 24), 256, 0, stream>>>(qkvbf, VT);
  fused_tok_attn<<<256, 512, 0, stream>>>(qkvbf, VT, o_tokattn, amh, attnout_bf);
  colmean_part<<<dim3(8, 2, 8), 256, 0, stream>>>(o_tokattn, amh, colpart);
  colmean_final<<<dim3(8, 2), 256, 0, stream>>>(colpart, wvec);

  // ---- ph3: token out projection + LN ----
  conv_bf16<<<288, 256, 0, stream>>>(Wo_t, wot, 73728);
  gemm_bf16<0><<<dim3(6, 32), 256, 0, stream>>>(attnout_bf, 768, wot, 768, bo_t, projbuf, 768, 768);
  ln_kernel<<<4096, 256, 0, stream>>>(hs, projbuf, g_tok, b_tok, tokout, tokout_bf);

  // ---- ph4: token->node aggregation + node attention (fused attn) ----
  aggregate_kernel<<<dim3(128, 2), 256, 0, stream>>>(tokout, wvec, t2s, nodepre, nodepre_bf);
  conv_bf16<<<864, 256, 0, stream>>>(Wqkv_t, wqkvt2, 221184);
  gemm_bf16<1><<<dim3(18, 2), 256, 0, stream>>>(nodepre_bf, 768, wqkvt2, 768, bqkv_t, nodeqkvbf, 2304, 768);
  attn_small<<<dim3(8, 2), 256, 0, stream>>>(
      nodeqkvbf, 2304, (long)128 * 2304,
      nodeqkvbf + 768, 2304, (long)128 * 2304,
      nodeqkvbf + 1536,
      nodeattn_bf, (long)128 * 768, o_nodeattn, 128);
  gemm_bf16<0><<<dim3(6, 2), 256, 0, stream>>>(nodeattn_bf, 768, wot, 768, bo_t, nodeproj, 768, 768);
  ln_kernel<<<256, 256, 0, stream>>>(nodepre, nodeproj, g_node, b_node, o_nodeemb, nodeemb_bf);

  // ---- ph5: cross projections ----
  conv_bf16<<<864, 256, 0, stream>>>(Wqkv_c, wqkvc, 221184);
  conv_bf16<<<288, 256, 0, stream>>>(Wo_c, woc, 73728);
  conv_bf16<<<288, 256, 0, stream>>>(W_out, wout, 73728);
  gemm_bf16<1><<<dim3(6, 32), 256, 0, stream>>>(tokout_bf, 768, wqkvc, 768, bqkv_c, crossqbf, 768, 768);
  gemm_bf16<1><<<dim3(12, 2), 256, 0, stream>>>(nodeemb_bf, 768, wqkvc + 768 * 768, 768, bqkv_c + 768,
                                                crosskvbf, 1536, 768);

  // ---- ph6: cross attention (fully fused) ----
  attn_small<<<dim3(128, 2), 256, 0, stream>>>(
      crossqbf, 768, (long)2048 * 768,
      crosskvbf, 1536, (long)128 * 1536,
      crosskvbf + 768,
      crossattn_bf, (long)2048 * 768, o_crossw, 2048);

  // ---- ph7: cross out projection, combine, final ----
  gemm_bf16<0><<<dim3(6, 32), 256, 0, stream>>>(crossattn_bf, 768, woc, 768, bo_c, crossproj, 768, 768);
  enhanced_kernel<<<1536, 256, 0, stream>>>(tokout, crossproj, o_nodeemb, t2s, enh_bf);
  gemm_bf16<0><<<dim3(6, 32), 256, 0, stream>>>(enh_bf, 768, wout, 768, b_out, o_output, 768, 768);
}